// Round 4
// baseline (97.085 us; speedup 1.0000x reference)
//
#include <hip/hip_runtime.h>
#include <stdint.h>

typedef _Float16 half8 __attribute__((ext_vector_type(8)));
typedef float floatx4 __attribute__((ext_vector_type(4)));
typedef uint32_t u32x4 __attribute__((ext_vector_type(4)));

#define BM 128
#define BN 128
#define BK 64
#define NT 512
#define KT_BASE 8      // 512/64 base-K tiles
#define KT_TOTAL 72    // 8 + 4096/64 spline-K tiles
#define IF 512
#define NF 512
#define SW_K 4096
#define TILE_B 16384   // bytes per 128x64 fp16 tile
#define WS_TILES (KT_TOTAL * 4)

__device__ __forceinline__ uint32_t swz(uint32_t b) {
  // rows are 128B; XOR byte bits [6:4] with (row&7) to kill ds_read_b128 bank conflicts
  return b ^ (((b >> 7) & 7u) << 4);
}

__device__ __forceinline__ uint32_t pk(float a, float b) {
  return __builtin_bit_cast(uint32_t, __builtin_amdgcn_cvt_pkrtz(a, b));
}

// ---- prepass: weights -> fp16 tile images, pre-swizzled for linear gload_lds
// ws[T*16K + q*16 .. +15] = B_linear_tile[swz(q*16) .. +15]  (swz involution)
__global__ __launch_bounds__(256)
void kan_prep(const float* __restrict__ bwg, const float* __restrict__ swg,
              uint32_t* __restrict__ wsB)
{
  const int gid = blockIdx.x * 256 + threadIdx.x;  // one per 16B chunk
  const int T = gid >> 10;          // tile 0..287
  const int q = gid & 1023;         // chunk in tile
  const int kt = T >> 2;            // 0..71
  const int nt = T & 3;
  const uint32_t p = swz((uint32_t)q * 16u);
  const int row = p >> 7;           // 0..127 (n within tile)
  const int c   = (p & 127) >> 1;   // 0..63  (k within tile, multiple of 8)
  const int n = nt * 128 + row;
  const float* src;
  if (kt < KT_BASE) src = bwg + (size_t)n * IF   + kt * 64 + c;
  else              src = swg + (size_t)n * SW_K + (kt - KT_BASE) * 64 + c;
  float4 f0 = ((const float4*)src)[0];
  float4 f1 = ((const float4*)src)[1];
  u32x4 v; v.x = pk(f0.x, f0.y); v.y = pk(f0.z, f0.w);
           v.z = pk(f1.x, f1.y); v.w = pk(f1.z, f1.w);
  *(u32x4*)((char*)wsB + (size_t)T * TILE_B + (size_t)q * 16) = v;
}

// ---------------------------- main fused kernel ------------------------------
__global__ __launch_bounds__(NT, 2)
void kan_fused(const float* __restrict__ xg, const uint32_t* __restrict__ wsB,
               float* __restrict__ outg)
{
  __shared__ _Float16 As[2][BM * BK];
  __shared__ _Float16 Bs[2][BN * BK];

  const int tid = threadIdx.x;
  const int lane = tid & 63;
  const int wv = tid >> 6;     // 0..7
  const int wm = wv >> 2;      // 0..1  (64-row strip)
  const int wn = wv & 3;       // 0..3  (32-col strip)

  // XCD-aware bijective block swizzle: 256 blocks, 8 XCDs, 32/XCD contiguous
  const int bid = blockIdx.x;
  const int lb = (bid & 7) * 32 + (bid >> 3);
  const int bm0 = (lb & 63) * BM;
  const int ntI = lb >> 6;          // n-tile index 0..3
  const int bn0 = ntI * BN;

  // A staging decode: thread owns 2 16B chunks: rows rT and rT+64, col chunk c8
  const int rT = tid >> 3;          // 0..63
  const int c8 = (tid & 7) * 8;     // element col (fp16 elems)
  const int ii = tid & 7;           // spline: which i within the 8-i K-tile
  const uint32_t wA0 = swz((uint32_t)rT * 128u + (uint32_t)c8 * 2u);
  const uint32_t wA1 = swz((uint32_t)(rT + 64) * 128u + (uint32_t)c8 * 2u);

  char* AsB = (char*)As;            // [2][16KB]
  char* BsB = (char*)Bs;            // [2][16KB]

  // fragment read offsets (kk=0); kk=1 is ^64 bytes (swizzle-safe XOR, NOT add)
  uint32_t rdA[4], rdB[2];
  {
    const int rr = lane & 15;
    const uint32_t cc = (uint32_t)(lane >> 4) * 16u;
#pragma unroll
    for (int mi = 0; mi < 4; ++mi)
      rdA[mi] = swz((uint32_t)(wm * 64 + mi * 16 + rr) * 128u + cc);
#pragma unroll
    for (int ni = 0; ni < 2; ++ni)
      rdB[ni] = swz((uint32_t)(wn * 32 + ni * 16 + rr) * 128u + cc);
  }

  floatx4 acc[4][2];
#pragma unroll
  for (int mi = 0; mi < 4; ++mi)
#pragma unroll
    for (int ni = 0; ni < 2; ++ni)
      acc[mi][ni] = (floatx4){0.f, 0.f, 0.f, 0.f};

  float4 aL[4];   // base-phase A fp32 staging
  float xv0, xv1; // spline-phase x values

  // async B tile DMA: ws tile (kt,ntI) -> Bs[nb], linear lane order
  auto GLOADB = [&](int kt, int nb) {
    const char* src = (const char*)wsB + (size_t)(kt * 4 + ntI) * TILE_B + (size_t)tid * 16;
    char* dst = BsB + nb * TILE_B + tid * 16;
    __builtin_amdgcn_global_load_lds(
        (const __attribute__((address_space(1))) uint32_t*)src,
        (__attribute__((address_space(3))) uint32_t*)dst, 16, 0, 0);
    __builtin_amdgcn_global_load_lds(
        (const __attribute__((address_space(1))) uint32_t*)(src + 8192),
        (__attribute__((address_space(3))) uint32_t*)(dst + 8192), 16, 0, 0);
  };

  auto LOADX = [&](int kt) {
    if (kt < KT_BASE) {
      const int kb = kt * 64;
      const float* a0 = xg + (size_t)(bm0 + rT) * IF + kb + c8;
      const float* a1 = a0 + (size_t)64 * IF;
      aL[0] = ((const float4*)a0)[0]; aL[1] = ((const float4*)a0)[1];
      aL[2] = ((const float4*)a1)[0]; aL[3] = ((const float4*)a1)[1];
    } else {
      const int i0 = (kt - KT_BASE) * 8;
      xv0 = xg[(size_t)(bm0 + rT) * IF + i0 + ii];
      xv1 = xg[(size_t)(bm0 + rT + 64) * IF + i0 + ii];
    }
  };

  // closed-form uniform cubic B-spline: grid = -2.2 + 0.4*t, h=0.4
  auto BASIS = [&](float xv) -> u32x4 {
    float u = (xv + 2.2f) * 2.5f;
    int j = (int)u;
    j = j < 3 ? 3 : (j > 7 ? 7 : j);
    float t = u - (float)j;
    float omt = 1.0f - t;
    float t2 = t * t, t3 = t2 * t;
    const float s6 = 0.16666666666666666f;
    float w0 = omt * omt * omt * s6;
    float w1 = (3.0f * t3 - 6.0f * t2 + 4.0f) * s6;
    float w2 = (-3.0f * t3 + 3.0f * t2 + 3.0f * t + 1.0f) * s6;
    float w3 = t3 * s6;
    uint32_t c0 = pk(w0, w1);
    uint32_t c1 = pk(w2, w3);
    const int j3 = j - 3;              // 0..4 : window start (halfword units)
    const bool odd = (j3 & 1) != 0;
    uint32_t lo  = odd ? (c0 << 16) : c0;
    uint32_t mid = odd ? ((c0 >> 16) | (c1 << 16)) : c1;
    uint32_t hi  = odd ? (c1 >> 16) : 0u;
    const int wofs = j3 >> 1;          // word offset 0..2
    u32x4 r;
    r.x = (wofs == 0) ? lo : 0u;
    r.y = (wofs == 0) ? mid : ((wofs == 1) ? lo : 0u);
    r.z = (wofs == 0) ? hi : ((wofs == 1) ? mid : lo);
    r.w = (wofs == 1) ? hi : ((wofs == 2) ? mid : 0u);
    return r;
  };

  auto WRITEA = [&](int kt, int nb) {
    char* base = AsB + nb * TILE_B;
    if (kt < KT_BASE) {
      u32x4 v0; v0.x = pk(aL[0].x, aL[0].y); v0.y = pk(aL[0].z, aL[0].w);
                v0.z = pk(aL[1].x, aL[1].y); v0.w = pk(aL[1].z, aL[1].w);
      u32x4 v1; v1.x = pk(aL[2].x, aL[2].y); v1.y = pk(aL[2].z, aL[2].w);
                v1.z = pk(aL[3].x, aL[3].y); v1.w = pk(aL[3].z, aL[3].w);
      *(u32x4*)(base + wA0) = v0;
      *(u32x4*)(base + wA1) = v1;
    } else {
      *(u32x4*)(base + wA0) = BASIS(xv0);
      *(u32x4*)(base + wA1) = BASIS(xv1);
    }
  };

  auto COMPUTE = [&](int cb) {
    const char* ab = AsB + cb * TILE_B;
    const char* bb = BsB + cb * TILE_B;
#pragma unroll
    for (int kk = 0; kk < 2; ++kk) {
      const uint32_t ko = (uint32_t)(kk * 64);
      half8 a[4], b[2];
#pragma unroll
      for (int mi = 0; mi < 4; ++mi)
        a[mi] = *(const half8*)(ab + (rdA[mi] ^ ko));
#pragma unroll
      for (int ni = 0; ni < 2; ++ni)
        b[ni] = *(const half8*)(bb + (rdB[ni] ^ ko));
#pragma unroll
      for (int mi = 0; mi < 4; ++mi)
#pragma unroll
        for (int ni = 0; ni < 2; ++ni)
          acc[mi][ni] = __builtin_amdgcn_mfma_f32_16x16x32_f16(a[mi], b[ni], acc[mi][ni], 0, 0, 0);
    }
  };

  // prologue: fill buffer 0
  LOADX(0);
  GLOADB(0, 0);
  WRITEA(0, 0);
  __syncthreads();   // drains vmcnt (gload_lds) + lgkm (ds_write)

#pragma unroll 1
  for (int kt = 0; kt < KT_TOTAL; ++kt) {
    const int cur = kt & 1;
    const int nxt = cur ^ 1;
    const bool more = (kt + 1) < KT_TOTAL;
    if (more) { GLOADB(kt + 1, nxt); LOADX(kt + 1); }  // async DMA + reg loads
    COMPUTE(cur);                                      // 12 ds_read + 16 MFMA
    if (more) WRITEA(kt + 1, nxt);                     // convert/basis + ds_write
    __syncthreads();                                   // one barrier per tile
  }

  // epilogue: C/D layout col=lane&15, row=(lane>>4)*4+e (m89/m91-verified)
  const int er = (lane >> 4) * 4;
  const int ec = lane & 15;
#pragma unroll
  for (int mi = 0; mi < 4; ++mi) {
#pragma unroll
    for (int ni = 0; ni < 2; ++ni) {
      const size_t base = (size_t)(bm0 + wm * 64 + mi * 16 + er) * NF
                        + (size_t)(bn0 + wn * 32 + ni * 16 + ec);
#pragma unroll
      for (int e = 0; e < 4; ++e)
        outg[base + (size_t)e * NF] = acc[mi][ni][e];
    }
  }
}

extern "C" void kernel_launch(void* const* d_in, const int* in_sizes, int n_in,
                              void* d_out, int out_size, void* d_ws, size_t ws_size,
                              hipStream_t stream) {
  const float* x  = (const float*)d_in[0];
  const float* bw = (const float*)d_in[1];
  const float* sw = (const float*)d_in[2];
  float* out = (float*)d_out;
  uint32_t* wsB = (uint32_t*)d_ws;   // needs 288*16KB = 4.5 MB
  hipLaunchKernelGGL(kan_prep, dim3(WS_TILES * 1024 / 256), dim3(256), 0, stream, bw, sw, wsB);
  hipLaunchKernelGGL(kan_fused, dim3(256), dim3(NT), 0, stream, x, wsB, out);
}

// Round 5
// 88.443 us; speedup vs baseline: 1.0977x; 1.0977x over previous
//
#include <hip/hip_runtime.h>
#include <stdint.h>

typedef _Float16 half8 __attribute__((ext_vector_type(8)));
typedef float floatx4 __attribute__((ext_vector_type(4)));
typedef uint32_t u32x4 __attribute__((ext_vector_type(4)));

#define BM 128
#define BN 128
#define BK 64
#define NT 512
#define KT_BASE 8      // 512/64 base-K tiles
#define KT_TOTAL 72    // 8 + 4096/64 spline-K tiles
#define KT_HALF 36     // split-K: 2 halves
#define IF 512
#define NF 512
#define SW_K 4096
#define TILE_B 16384   // bytes per 128x64 fp16 tile
#define WS_TILES (KT_TOTAL * 4)

__device__ __forceinline__ uint32_t swz(uint32_t b) {
  // rows are 128B; XOR byte bits [6:4] with (row&7) to kill ds_read_b128 bank conflicts
  return b ^ (((b >> 7) & 7u) << 4);
}

__device__ __forceinline__ uint32_t pk(float a, float b) {
  return __builtin_bit_cast(uint32_t, __builtin_amdgcn_cvt_pkrtz(a, b));
}

// ---- zero d_out (stream-ordered before main kernel) ----
__global__ __launch_bounds__(256)
void kan_zero(float4* __restrict__ p, int n4) {
  const int stride = gridDim.x * 256;
  for (int i = blockIdx.x * 256 + threadIdx.x; i < n4; i += stride)
    p[i] = (float4){0.f, 0.f, 0.f, 0.f};
}

// ---- prepass: weights -> fp16 tile images, pre-swizzled for linear gload_lds
__global__ __launch_bounds__(256)
void kan_prep(const float* __restrict__ bwg, const float* __restrict__ swg,
              uint32_t* __restrict__ wsB)
{
  const int gid = blockIdx.x * 256 + threadIdx.x;  // one per 16B chunk
  const int T = gid >> 10;          // tile 0..287
  const int q = gid & 1023;         // chunk in tile
  const int kt = T >> 2;            // 0..71
  const int nt = T & 3;
  const uint32_t p = swz((uint32_t)q * 16u);
  const int row = p >> 7;           // 0..127 (n within tile)
  const int c   = (p & 127) >> 1;   // 0..63  (k within tile, multiple of 8)
  const int n = nt * 128 + row;
  const float* src;
  if (kt < KT_BASE) src = bwg + (size_t)n * IF   + kt * 64 + c;
  else              src = swg + (size_t)n * SW_K + (kt - KT_BASE) * 64 + c;
  float4 f0 = ((const float4*)src)[0];
  float4 f1 = ((const float4*)src)[1];
  u32x4 v; v.x = pk(f0.x, f0.y); v.y = pk(f0.z, f0.w);
           v.z = pk(f1.x, f1.y); v.w = pk(f1.z, f1.w);
  *(u32x4*)((char*)wsB + (size_t)T * TILE_B + (size_t)q * 16) = v;
}

// ---------------------------- main fused kernel ------------------------------
__global__ __launch_bounds__(NT, 2)
void kan_fused(const float* __restrict__ xg, const uint32_t* __restrict__ wsB,
               float* __restrict__ outg)
{
  __shared__ _Float16 As[2][BM * BK];
  __shared__ _Float16 Bs[2][BN * BK];

  const int tid = threadIdx.x;
  const int lane = tid & 63;
  const int wv = tid >> 6;     // 0..7
  const int wm = wv >> 2;      // 0..1  (64-row strip)
  const int wn = wv & 3;       // 0..3  (32-col strip)

  // 512 blocks -> 8 XCDs x 64; u -> (kz, tile) bijective
  const int bid = blockIdx.x;
  const int u = (bid & 7) * 64 + (bid >> 3);
  const int kz = u & 1;             // K-split half
  const int lb = u >> 1;            // 0..255 tile id
  const int bm0 = (lb & 63) * BM;
  const int ntI = lb >> 6;          // n-tile index 0..3
  const int bn0 = ntI * BN;
  const int kt0 = kz * KT_HALF;
  const int kt1 = kt0 + KT_HALF;

  // A staging decode: thread owns 2 16B chunks: rows rT and rT+64, col chunk c8
  const int rT = tid >> 3;          // 0..63
  const int c8 = (tid & 7) * 8;     // element col (fp16 elems)
  const int ii = tid & 7;           // spline: which i within the 8-i K-tile
  const uint32_t wA0 = swz((uint32_t)rT * 128u + (uint32_t)c8 * 2u);
  const uint32_t wA1 = swz((uint32_t)(rT + 64) * 128u + (uint32_t)c8 * 2u);

  char* AsB = (char*)As;            // [2][16KB]
  char* BsB = (char*)Bs;            // [2][16KB]

  // fragment read offsets (kk=0); kk=1 is ^64 bytes (swizzle-safe XOR, NOT add)
  uint32_t rdA[4], rdB[2];
  {
    const int rr = lane & 15;
    const uint32_t cc = (uint32_t)(lane >> 4) * 16u;
#pragma unroll
    for (int mi = 0; mi < 4; ++mi)
      rdA[mi] = swz((uint32_t)(wm * 64 + mi * 16 + rr) * 128u + cc);
#pragma unroll
    for (int ni = 0; ni < 2; ++ni)
      rdB[ni] = swz((uint32_t)(wn * 32 + ni * 16 + rr) * 128u + cc);
  }

  floatx4 acc[4][2];
#pragma unroll
  for (int mi = 0; mi < 4; ++mi)
#pragma unroll
    for (int ni = 0; ni < 2; ++ni)
      acc[mi][ni] = (floatx4){0.f, 0.f, 0.f, 0.f};

  float4 aL[4];   // base-phase A fp32 staging
  float xv0, xv1; // spline-phase x values

  // async B tile DMA: ws tile (kt,ntI) -> Bs[nb], linear lane order
  auto GLOADB = [&](int kt, int nb) {
    const char* src = (const char*)wsB + (size_t)(kt * 4 + ntI) * TILE_B + (size_t)tid * 16;
    char* dst = BsB + nb * TILE_B + tid * 16;
    __builtin_amdgcn_global_load_lds(
        (const __attribute__((address_space(1))) uint32_t*)src,
        (__attribute__((address_space(3))) uint32_t*)dst, 16, 0, 0);
    __builtin_amdgcn_global_load_lds(
        (const __attribute__((address_space(1))) uint32_t*)(src + 8192),
        (__attribute__((address_space(3))) uint32_t*)(dst + 8192), 16, 0, 0);
  };

  auto LOADX = [&](int kt) {
    if (kt < KT_BASE) {
      const int kb = kt * 64;
      const float* a0 = xg + (size_t)(bm0 + rT) * IF + kb + c8;
      const float* a1 = a0 + (size_t)64 * IF;
      aL[0] = ((const float4*)a0)[0]; aL[1] = ((const float4*)a0)[1];
      aL[2] = ((const float4*)a1)[0]; aL[3] = ((const float4*)a1)[1];
    } else {
      const int i0 = (kt - KT_BASE) * 8;
      xv0 = xg[(size_t)(bm0 + rT) * IF + i0 + ii];
      xv1 = xg[(size_t)(bm0 + rT + 64) * IF + i0 + ii];
    }
  };

  // closed-form uniform cubic B-spline: grid = -2.2 + 0.4*t, h=0.4
  auto BASIS = [&](float xv) -> u32x4 {
    float u2 = (xv + 2.2f) * 2.5f;
    int j = (int)u2;
    j = j < 3 ? 3 : (j > 7 ? 7 : j);
    float t = u2 - (float)j;
    float omt = 1.0f - t;
    float t2 = t * t, t3 = t2 * t;
    const float s6 = 0.16666666666666666f;
    float w0 = omt * omt * omt * s6;
    float w1 = (3.0f * t3 - 6.0f * t2 + 4.0f) * s6;
    float w2 = (-3.0f * t3 + 3.0f * t2 + 3.0f * t + 1.0f) * s6;
    float w3 = t3 * s6;
    uint32_t c0 = pk(w0, w1);
    uint32_t c1 = pk(w2, w3);
    const int j3 = j - 3;              // 0..4 : window start (halfword units)
    const bool odd = (j3 & 1) != 0;
    uint32_t lo  = odd ? (c0 << 16) : c0;
    uint32_t mid = odd ? ((c0 >> 16) | (c1 << 16)) : c1;
    uint32_t hi  = odd ? (c1 >> 16) : 0u;
    const int wofs = j3 >> 1;          // word offset 0..2
    u32x4 r;
    r.x = (wofs == 0) ? lo : 0u;
    r.y = (wofs == 0) ? mid : ((wofs == 1) ? lo : 0u);
    r.z = (wofs == 0) ? hi : ((wofs == 1) ? mid : lo);
    r.w = (wofs == 1) ? hi : ((wofs == 2) ? mid : 0u);
    return r;
  };

  auto WRITEA = [&](int kt, int nb) {
    char* base = AsB + nb * TILE_B;
    if (kt < KT_BASE) {
      u32x4 v0; v0.x = pk(aL[0].x, aL[0].y); v0.y = pk(aL[0].z, aL[0].w);
                v0.z = pk(aL[1].x, aL[1].y); v0.w = pk(aL[1].z, aL[1].w);
      u32x4 v1; v1.x = pk(aL[2].x, aL[2].y); v1.y = pk(aL[2].z, aL[2].w);
                v1.z = pk(aL[3].x, aL[3].y); v1.w = pk(aL[3].z, aL[3].w);
      *(u32x4*)(base + wA0) = v0;
      *(u32x4*)(base + wA1) = v1;
    } else {
      *(u32x4*)(base + wA0) = BASIS(xv0);
      *(u32x4*)(base + wA1) = BASIS(xv1);
    }
  };

  auto COMPUTE = [&](int cb) {
    const char* ab = AsB + cb * TILE_B;
    const char* bb = BsB + cb * TILE_B;
#pragma unroll
    for (int kk = 0; kk < 2; ++kk) {
      const uint32_t ko = (uint32_t)(kk * 64);
      half8 a[4], b[2];
#pragma unroll
      for (int mi = 0; mi < 4; ++mi)
        a[mi] = *(const half8*)(ab + (rdA[mi] ^ ko));
#pragma unroll
      for (int ni = 0; ni < 2; ++ni)
        b[ni] = *(const half8*)(bb + (rdB[ni] ^ ko));
#pragma unroll
      for (int mi = 0; mi < 4; ++mi)
#pragma unroll
        for (int ni = 0; ni < 2; ++ni)
          acc[mi][ni] = __builtin_amdgcn_mfma_f32_16x16x32_f16(a[mi], b[ni], acc[mi][ni], 0, 0, 0);
    }
  };

  // prologue: fill buffer 0 with tile kt0
  LOADX(kt0);
  GLOADB(kt0, 0);
  WRITEA(kt0, 0);
  __syncthreads();   // drains vmcnt (gload_lds) + lgkm (ds_write)

#pragma unroll 1
  for (int kt = kt0; kt < kt1; ++kt) {
    const int cur = kt & 1;
    const int nxt = cur ^ 1;
    const bool more = (kt + 1) < kt1;
    if (more) { GLOADB(kt + 1, nxt); LOADX(kt + 1); }  // async DMA + reg loads
    COMPUTE(cur);                                      // 12 ds_read + 16 MFMA
    if (more) WRITEA(kt + 1, nxt);                     // convert/basis + ds_write
    __syncthreads();                                   // one barrier per tile
  }

  // epilogue: atomic accumulate (2 commutative contributions per element)
  const int er = (lane >> 4) * 4;
  const int ec = lane & 15;
#pragma unroll
  for (int mi = 0; mi < 4; ++mi) {
#pragma unroll
    for (int ni = 0; ni < 2; ++ni) {
      const size_t base = (size_t)(bm0 + wm * 64 + mi * 16 + er) * NF
                        + (size_t)(bn0 + wn * 32 + ni * 16 + ec);
#pragma unroll
      for (int e = 0; e < 4; ++e)
        unsafeAtomicAdd(outg + base + (size_t)e * NF, acc[mi][ni][e]);
    }
  }
}

extern "C" void kernel_launch(void* const* d_in, const int* in_sizes, int n_in,
                              void* d_out, int out_size, void* d_ws, size_t ws_size,
                              hipStream_t stream) {
  const float* x  = (const float*)d_in[0];
  const float* bw = (const float*)d_in[1];
  const float* sw = (const float*)d_in[2];
  float* out = (float*)d_out;
  uint32_t* wsB = (uint32_t*)d_ws;   // 288*16KB = 4.5 MB
  hipLaunchKernelGGL(kan_zero, dim3(2048), dim3(256), 0, stream, (float4*)out, out_size / 4);
  hipLaunchKernelGGL(kan_prep, dim3(WS_TILES * 1024 / 256), dim3(256), 0, stream, bw, sw, wsB);
  hipLaunchKernelGGL(kan_fused, dim3(512), dim3(NT), 0, stream, x, wsB, out);
}